// Round 6
// baseline (150.150 us; speedup 1.0000x reference)
//
#include <hip/hip_runtime.h>
#include <hip/hip_bf16.h>

// Windowed attention smoothing, all-MFMA, rows=200000, RANK=64, WINDOW=11.
// Block=256 (4 waves), 16 rows/wave, one 64-row tile per block (3125 blocks).
//
// Designed to the measured occupancy buckets (m68/m69: wave slots halve at
// total-reg 64/128): total regs <= 64 AND LDS = 20480 B => 8 blocks/CU.
//  - A window (80 rows) staged ONCE block-cooperatively to LDS, transposed
//    (A_T[col][slot]) => P4's MFMA B-fragments are aligned uint4 reads.
//  - M1 computed transposed (C[col][q] = W @ A^T): V1 epilogue = packed b64
//    LDS writes; bias via float4.
//  - M2 (banded scores) reuses abnd regs + V1 LDS frags; scores stay in
//    registers — softmax combines across the 4 lanes {q,q+16,q+32,q+48}
//    with 4 shfl_xor; band-mask via -1e30 sentinel (no Sc LDS).
//  - P (probability band matrix) written to LDS as zero-padded bf16 PAIRS
//    (uint writes, no RMW), then P4 = 4 MFMAs + quarter-coalesced stores.
// All LDS is uint-typed (V1/P overlap is same-type => ordering preserved).
// One __syncthreads (after staging); everything else wave-autonomous.

constexpr int RANK  = 64;
constexpr int PAD   = 5;
constexpr int BLOCK = 256;
constexpr int TR    = 64;    // rows per block

typedef short short8  __attribute__((ext_vector_type(8)));
typedef float float4v __attribute__((ext_vector_type(4)));

constexpr int AT_S = 44;   // uint per A_T row (88 bf16; 176 B, 16B-mult)
constexpr int VP_S = 36;   // uint per V1/P row (72 bf16; 144 B, 16B-mult)

__device__ __forceinline__ unsigned int pack2(float lo, float hi) {
    union { __hip_bfloat162 h; unsigned int u; } c;
    c.h = __float22bfloat162_rn(make_float2(lo, hi));
    return c.u;   // low short = lo (even col), high = hi (odd col)
}

__device__ __forceinline__ short8 cvt_bf8(float4 a, float4 b) {
    union { short8 s; unsigned int u[4]; } c;
    c.u[0] = pack2(a.x, a.y); c.u[1] = pack2(a.z, a.w);
    c.u[2] = pack2(b.x, b.y); c.u[3] = pack2(b.z, b.w);
    return c.s;
}

__device__ __forceinline__ short8 load_afrag(const float* __restrict__ A,
                                             int row, int col0, int rows) {
    if ((unsigned)row < (unsigned)rows) {
        const float4* p = (const float4*)(A + (size_t)row * RANK + col0);
        return cvt_bf8(p[0], p[1]);
    }
    return (short8)0;   // zero pad rows (jnp.pad semantics: score 0)
}

__device__ __forceinline__ float fast_tanh(float x) {
    return 1.0f - 2.0f / (1.0f + __expf(2.0f * x));
}

__global__ __launch_bounds__(BLOCK, 8) void attn_win_kernel(
    const float* __restrict__ A,   // (rows, 64)
    const float* __restrict__ W,   // (64, 64) row-major (out,in)
    const float* __restrict__ b,   // (64,)
    float* __restrict__ out,       // (rows, 64)
    int rows)
{
    // 11264 + 9216 = 20480 B total => 8 blocks/CU on 160 KiB LDS.
    __shared__ unsigned int ATu[RANK][AT_S];  // A_T[col][slot/2], bf16 pairs
    __shared__ unsigned int VPu[4][16][VP_S]; // per-wave V1 rows; P reuses cols 0..31

    const int lane = threadIdx.x & 63;
    const int wv   = threadIdx.x >> 6;
    const int m16  = lane & 15;
    const int quad = lane >> 4;
    const int rw0  = blockIdx.x * TR;
    const int rw   = rw0 + wv * 16;            // this wave's rows rw..rw+15

    // ---- Stage A window transposed: slot s (0..79) <-> global row rw0-5+s.
    // Wave wv stages slots [20wv, 20wv+19]; lane = column; pairs packed.
    #pragma unroll
    for (int k = 0; k < 10; k++) {
        const int s  = wv * 20 + 2 * k;
        const int g0 = rw0 - PAD + s;
        float f0 = ((unsigned)g0       < (unsigned)rows) ? A[(size_t)g0 * RANK + lane]       : 0.0f;
        float f1 = ((unsigned)(g0 + 1) < (unsigned)rows) ? A[(size_t)(g0 + 1) * RANK + lane] : 0.0f;
        ATu[lane][wv * 10 + k] = pack2(f0, f1);
    }
    __syncthreads();

    // ---- B-operand fragments for M1: A rows rw+m16 (global, L1-hot) ----
    short8 am1[2];
    #pragma unroll
    for (int kf = 0; kf < 2; kf++)
        am1[kf] = load_afrag(A, rw + m16, kf * 32 + quad * 8, rows);

    // ---- M1 (transposed): C[col][q] = sum_k W[col][k] A[rw+q][k] + b[col] ----
    // Streamed per ct to bound register pressure. Lane holds
    // V1[q=m16][col=ct*16+quad*4+rg]; packed pair-writes to VPu.
    #pragma unroll
    for (int ct = 0; ct < 4; ct++) {
        const float4 bb = *(const float4*)(b + ct * 16 + quad * 4);
        float4v acc = (float4v){bb.x, bb.y, bb.z, bb.w};
        #pragma unroll
        for (int kf = 0; kf < 2; kf++) {
            const float4* wp =
                (const float4*)(W + (ct * 16 + m16) * RANK + kf * 32 + quad * 8);
            const short8 wf = cvt_bf8(wp[0], wp[1]);
            acc = __builtin_amdgcn_mfma_f32_16x16x32_bf16(wf, am1[kf], acc, 0, 0, 0);
        }
        const unsigned int u0 = pack2(fast_tanh(acc[0]), fast_tanh(acc[1]));
        const unsigned int u1 = pack2(fast_tanh(acc[2]), fast_tanh(acc[3]));
        *(uint2*)&VPu[wv][m16][ct * 8 + quad * 2] = make_uint2(u0, u1);
    }

    // ---- M2: S[i][q] = dot(Awin[i], v1[q]) * 0.125 (kept in registers) ----
    short8 abnd[2][2];
    #pragma unroll
    for (int it = 0; it < 2; it++)
        #pragma unroll
        for (int kf = 0; kf < 2; kf++)
            abnd[it][kf] = load_afrag(A, rw - PAD + it * 16 + m16,
                                      kf * 32 + quad * 8, rows);
    short8 v1f[2];
    #pragma unroll
    for (int kf = 0; kf < 2; kf++) {
        const uint4 t = *(const uint4*)&VPu[wv][m16][kf * 16 + quad * 4];
        v1f[kf] = *(const short8*)&t;
    }
    float4v sacc[2];
    sacc[0] = (float4v){0.f, 0.f, 0.f, 0.f};
    sacc[1] = (float4v){0.f, 0.f, 0.f, 0.f};
    #pragma unroll
    for (int kf = 0; kf < 2; kf++)
        #pragma unroll
        for (int it = 0; it < 2; it++)
            sacc[it] = __builtin_amdgcn_mfma_f32_16x16x32_bf16(
                abnd[it][kf], v1f[kf], sacc[it], 0, 0, 0);
    // Lane(m16=q, quad) holds S[i = it*16 + quad*4 + rg][q].

    // ---- softmax over band i in [q, q+10]; cooperative across quads ----
    float sm[2][4], e[2][4];
    float mloc = -1e30f;
    #pragma unroll
    for (int it = 0; it < 2; it++)
        #pragma unroll
        for (int rg = 0; rg < 4; rg++) {
            const int i = it * 16 + quad * 4 + rg;
            const bool inb = (i >= m16) && (i <= m16 + 10);
            sm[it][rg] = inb ? sacc[it][rg] * 0.125f : -1e30f;
            mloc = fmaxf(mloc, sm[it][rg]);
        }
    mloc = fmaxf(mloc, __shfl_xor(mloc, 16));
    mloc = fmaxf(mloc, __shfl_xor(mloc, 32));
    float dloc = 0.0f;
    #pragma unroll
    for (int it = 0; it < 2; it++)
        #pragma unroll
        for (int rg = 0; rg < 4; rg++) {
            e[it][rg] = __expf(sm[it][rg] - mloc);  // out-of-band -> 0
            dloc += e[it][rg];
        }
    dloc += __shfl_xor(dloc, 16);
    dloc += __shfl_xor(dloc, 32);
    const float rden = __fdividef(1.0f, dloc);

    // ---- P matrix to LDS (row q=m16, cols i=0..31), zero-padded pairs ----
    // Quads tile the 32 cols: it*16+4*quad+{0..3}; writes cover everything,
    // so no separate zero-init. Overwrites V1 rows (dead, same-type array).
    #pragma unroll
    for (int it = 0; it < 2; it++) {
        const unsigned int u0 = pack2(e[it][0] * rden, e[it][1] * rden);
        const unsigned int u1 = pack2(e[it][2] * rden, e[it][3] * rden);
        *(uint2*)&VPu[wv][m16][it * 8 + quad * 2] = make_uint2(u0, u1);
    }

    // ---- P4: out[rw+rr] = sum_i P[rr][i] * Awin_block[wv*16+i] ----
    short8 pfrag;
    {
        const uint4 t = *(const uint4*)&VPu[wv][m16][quad * 4];
        pfrag = *(const short8*)&t;
    }
    #pragma unroll
    for (int ct = 0; ct < 4; ct++) {
        const uint4 t = *(const uint4*)&ATu[ct * 16 + m16][wv * 8 + quad * 4];
        const short8 bfr = *(const short8*)&t;
        float4v oacc = (float4v){0.f, 0.f, 0.f, 0.f};
        oacc = __builtin_amdgcn_mfma_f32_16x16x32_bf16(pfrag, bfr, oacc, 0, 0, 0);
        #pragma unroll
        for (int rg = 0; rg < 4; rg++) {
            const int r = rw + quad * 4 + rg;
            if (r < rows) out[(size_t)r * RANK + ct * 16 + m16] = oacc[rg];
        }
    }
}

extern "C" void kernel_launch(void* const* d_in, const int* in_sizes, int n_in,
                              void* d_out, int out_size, void* d_ws, size_t ws_size,
                              hipStream_t stream) {
    const float* A = (const float*)d_in[0];
    const float* W = (const float*)d_in[1];
    const float* b = (const float*)d_in[2];
    float* out = (float*)d_out;

    const int rows   = in_sizes[0] / RANK;
    const int blocks = (rows + TR - 1) / TR;

    hipLaunchKernelGGL(attn_win_kernel, dim3(blocks), dim3(BLOCK), 0, stream,
                       A, W, b, out, rows);
}